// Round 1
// baseline (200.335 us; speedup 1.0000x reference)
//
#include <hip/hip_runtime.h>

typedef _Float16 f16;
typedef f16 f16x8 __attribute__((ext_vector_type(8)));
typedef f16 f16x4 __attribute__((ext_vector_type(4)));
typedef __fp16 h16x2 __attribute__((ext_vector_type(2)));   // cvt_pkrtz native type
typedef float f32x4 __attribute__((ext_vector_type(4)));
typedef float f32x2 __attribute__((ext_vector_type(2)));

#define MFMA16(A, B, C) __builtin_amdgcn_mfma_f32_16x16x32_f16((A), (B), (C), 0, 0, 0)

// Barrier WITHOUT vmcnt drain: only LDS (lgkmcnt) must be visible across it.
// (R6: LDS flag sync is WORSE than s_barrier; __syncthreads would drain vmcnt
// and serialize the in-flight x prefetch.)
#define LDS_BARRIER() asm volatile("s_waitcnt lgkmcnt(0)\n\ts_barrier" ::: "memory")

__device__ __forceinline__ float E2(float x) {   // 2^x
#if __has_builtin(__builtin_amdgcn_exp2f)
  return __builtin_amdgcn_exp2f(x);
#else
  return __expf(x * 0.69314718056f);
#endif
}

__device__ __forceinline__ f16x8 cvt8(float4 a, float4 b) {
  union { h16x2 h[4]; f16x8 v; } u;
  u.h[0] = __builtin_amdgcn_cvt_pkrtz(a.x, a.y);
  u.h[1] = __builtin_amdgcn_cvt_pkrtz(a.z, a.w);
  u.h[2] = __builtin_amdgcn_cvt_pkrtz(b.x, b.y);
  u.h[3] = __builtin_amdgcn_cvt_pkrtz(b.z, b.w);
  return u.v;
}

// scaled weight-load convert (init-time only)
__device__ __forceinline__ f16x8 cvt8s(const float* p, float s) {
  float4 a = *(const float4*)p;
  float4 b = *(const float4*)(p + 4);
  union { h16x2 h[4]; f16x8 v; } u;
  u.h[0] = __builtin_amdgcn_cvt_pkrtz(a.x * s, a.y * s);
  u.h[1] = __builtin_amdgcn_cvt_pkrtz(a.z * s, a.w * s);
  u.h[2] = __builtin_amdgcn_cvt_pkrtz(b.x * s, b.y * s);
  u.h[3] = __builtin_amdgcn_cvt_pkrtz(b.z * s, b.w * s);
  return u.v;
}

__device__ __forceinline__ f16x4 pack4(f32x2 a, f32x2 b) {
  union { h16x2 h2[2]; f16x4 v; } u;
  u.h2[0] = __builtin_amdgcn_cvt_pkrtz(a[0], a[1]);
  u.h2[1] = __builtin_amdgcn_cvt_pkrtz(b[0], b[1]);
  return u.v;
}

// Packed gate math for a pair of h-rows.  float2 ops -> v_pk_*_f32.
// R7: gate pre-scales are FOLDED INTO THE WEIGHTS/BIASES at load time:
//   aR,aZ arrive already multiplied by -log2(e)   -> ea = 2^aR = e^{-pre_r}
//   aXN,aHN arrive already multiplied by -2log2(e) -> my = aXN + r*aHN = -2log2e*y
// This removes the 3 pk-muls (mR, mZ, my-scale) and puts exp2 directly after MFMA.
// sigmoid pair shares one rcp per row; tanh(y) = (1-c)*rcp(1+c), c = 2^(-2*log2e*y).
__device__ __forceinline__ void gates_pair(f32x2 aR, f32x2 aZ, f32x2 aXN,
                                           f32x2 aHN, f32x2& hs) {
  f32x2 ea, eb;
  ea[0] = E2(aR[0]); ea[1] = E2(aR[1]);
  eb[0] = E2(aZ[0]); eb[1] = E2(aZ[1]);
  f32x2 pa = ea + 1.0f;
  f32x2 pb = eb + 1.0f;
  f32x2 prod = pa * pb;
  f32x2 inv;
  inv[0] = __builtin_amdgcn_rcpf(prod[0]);
  inv[1] = __builtin_amdgcn_rcpf(prod[1]);
  f32x2 rg = pb * inv;                 // sigmoid(r pre-act)
  f32x2 zg = pa * inv;                 // sigmoid(z pre-act)
  f32x2 my = aXN + rg * aHN;           // = -2*log2e * (xn + r*hn)
  f32x2 c;
  c[0] = E2(my[0]); c[1] = E2(my[1]);
  f32x2 num = 1.0f - c;
  f32x2 den = 1.0f + c;
  f32x2 rin;
  rin[0] = __builtin_amdgcn_rcpf(den[0]);
  rin[1] = __builtin_amdgcn_rcpf(den[1]);
  f32x2 ng = num * rin;                // tanh(y)
  hs = zg * (hs - ng) + ng;
}

// B=4096, T=128, D=32, H=64.  16 batch / WG, 4 waves (R7 merged-role design).
//
// R7 structural change: instead of 4 layer-0 waves + 4 layer-1 waves in
// lockstep on one barrier (2 waves/SIMD, both stalling at the same points ->
// VALUBusy 45%, 55% idle), each wave now owns rows [16w,16w+16) of BOTH
// layers: per interval it runs layer-0 step t AND layer-1 step t-1 — two
// INDEPENDENT dependency chains interleaved in one instruction stream.
// The B-chain's MFMAs/trans fill the A-chain's ds_read/exp latency and vice
// versa.  Both roles consume the same H0[p] fragments (h0(t-1)), so they are
// loaded ONCE per wave (LDS reads 24 -> 16 per group-interval).  Barrier now
// syncs 4 waves instead of 8.
//
// Time loop unrolled x2 so ping-pong parity and prefetch slots are
// compile-time constants (R4: runtime-indexed arrays -> scratch).  One
// LDS-only s_barrier per pipeline step (R5 structure).
// H LDS layout: h[k] for batch b at f16 offset ((k>>3)*16+b)*8 + (k&7)
//   -> B-frag for lane L, kfrag f = stride-1 ds_read_b128 at f*1024 + L*16.
__launch_bounds__(256, 1)
__global__ void gru_fused(const float* __restrict__ x,
                          const float* __restrict__ Wih0, const float* __restrict__ Whh0,
                          const float* __restrict__ bih0, const float* __restrict__ bhh0,
                          const float* __restrict__ Wih1, const float* __restrict__ Whh1,
                          const float* __restrict__ bih1, const float* __restrict__ bhh1,
                          const float* __restrict__ fcw, const float* __restrict__ fcb,
                          float* __restrict__ out) {
  __shared__ f16 H0[2][1024];
  __shared__ f16 H1[2][1024];
  __shared__ float red[4][16];

  const int tid = threadIdx.x;
  const int wave = tid >> 6;          // 0..3
  const int lane = tid & 63;
  const int l15 = lane & 15;
  const int q = lane >> 4;
  const int b0 = blockIdx.x * 16;

  for (int i = tid; i < 2048; i += 256) {
    ((f16*)H0)[i] = (f16)0.0f;
    ((f16*)H1)[i] = (f16)0.0f;
  }

  const float SRZ = -1.44269504f;     // -log2(e)      folded into r,z rows
  const float SN  = -2.88539008f;     // -2*log2(e)    folded into n rows

  // ---- register-resident weight A-fragments for BOTH layers:
  //      A[m=l15][k = kf*32 + q*8 + j], rows g*64 + 16*wave + l15
  f16x8 wAx[3];          // layer0 Wih (K=32)
  f16x8 wAh[3][2];       // layer0 Whh (K=64)
  f16x8 wBx[3][2];       // layer1 Wih (K=64)
  f16x8 wBh[3][2];       // layer1 Whh (K=64)
  f32x4 bRA, bZA, bXNA, bHNA;
  f32x4 bRB, bZB, bXNB, bHNB;
  float fw[4];

#pragma unroll
  for (int g = 0; g < 3; ++g) {
    const float s = (g == 2) ? SN : SRZ;
    const int row = g * 64 + 16 * wave + l15;
    wAx[g] = cvt8s(Wih0 + row * 32 + q * 8, s);
#pragma unroll
    for (int kf = 0; kf < 2; ++kf) {
      wAh[g][kf] = cvt8s(Whh0 + row * 64 + kf * 32 + q * 8, s);
      wBx[g][kf] = cvt8s(Wih1 + row * 64 + kf * 32 + q * 8, s);
      wBh[g][kf] = cvt8s(Whh1 + row * 64 + kf * 32 + q * 8, s);
    }
  }
#pragma unroll
  for (int r = 0; r < 4; ++r) {
    const int o = 16 * wave + 4 * q + r;
    bRA[r]  = SRZ * (bih0[o] + bhh0[o]);
    bZA[r]  = SRZ * (bih0[64 + o] + bhh0[64 + o]);
    bXNA[r] = SN * bih0[128 + o];
    bHNA[r] = SN * bhh0[128 + o];
    bRB[r]  = SRZ * (bih1[o] + bhh1[o]);
    bZB[r]  = SRZ * (bih1[64 + o] + bhh1[64 + o]);
    bXNB[r] = SN * bih1[128 + o];
    bHNB[r] = SN * bhh1[128 + o];
    fw[r] = fcw[o];
  }
  const float fcb0 = fcb[0];

  f32x2 hA01 = {0.f, 0.f}, hA23 = {0.f, 0.f};   // layer0 state, this lane's 4 rows
  f32x2 hB01 = {0.f, 0.f}, hB23 = {0.f, 0.f};   // layer1 state

  const int wk0 = 16 * wave + 4 * q;
  const int widx = ((wk0 >> 3) * 16 + l15) * 8 + (wk0 & 7);

  // layer-0 step: consume shared H0[p] frags + x frag, write H0[p^1]
  auto stepA = [&](f16x8 g0, f16x8 g1, f16* H0w, float4 xav, float4 xbv) {
    const f16x8 xf = cvt8(xav, xbv);
    f32x4 aR  = MFMA16(wAx[0], xf, bRA);
    f32x4 aZ  = MFMA16(wAx[1], xf, bZA);
    f32x4 aXN = MFMA16(wAx[2], xf, bXNA);
    f32x4 aHN = MFMA16(wAh[2][0], g0, bHNA);
    aR  = MFMA16(wAh[0][0], g0, aR);
    aZ  = MFMA16(wAh[1][0], g0, aZ);
    aR  = MFMA16(wAh[0][1], g1, aR);
    aZ  = MFMA16(wAh[1][1], g1, aZ);
    aHN = MFMA16(wAh[2][1], g1, aHN);
    gates_pair(f32x2{aR[0], aR[1]}, f32x2{aZ[0], aZ[1]},
               f32x2{aXN[0], aXN[1]}, f32x2{aHN[0], aHN[1]}, hA01);
    gates_pair(f32x2{aR[2], aR[3]}, f32x2{aZ[2], aZ[3]},
               f32x2{aXN[2], aXN[3]}, f32x2{aHN[2], aHN[3]}, hA23);
    *(f16x4*)&H0w[widx] = pack4(hA01, hA23);
  };

  // layer-1 step: consume the SAME H0[p] frags (h0(t-1)) + own state H1[p],
  // write H1[p^1]
  auto stepB = [&](f16x8 g0, f16x8 g1, const f16* H1r, f16* H1w) {
    const f16x8 h1f0 = *(const f16x8*)&H1r[lane * 8];
    const f16x8 h1f1 = *(const f16x8*)&H1r[512 + lane * 8];
    f32x4 aR  = MFMA16(wBx[0][0], g0, bRB);
    f32x4 aZ  = MFMA16(wBx[1][0], g0, bZB);
    f32x4 aXN = MFMA16(wBx[2][0], g0, bXNB);
    aR  = MFMA16(wBx[0][1], g1, aR);
    aZ  = MFMA16(wBx[1][1], g1, aZ);
    aXN = MFMA16(wBx[2][1], g1, aXN);
    f32x4 aHN = MFMA16(wBh[2][0], h1f0, bHNB);
    aR  = MFMA16(wBh[0][0], h1f0, aR);
    aZ  = MFMA16(wBh[1][0], h1f0, aZ);
    aR  = MFMA16(wBh[0][1], h1f1, aR);
    aZ  = MFMA16(wBh[1][1], h1f1, aZ);
    aHN = MFMA16(wBh[2][1], h1f1, aHN);
    gates_pair(f32x2{aR[0], aR[1]}, f32x2{aZ[0], aZ[1]},
               f32x2{aXN[0], aXN[1]}, f32x2{aHN[0], aHN[1]}, hB01);
    gates_pair(f32x2{aR[2], aR[3]}, f32x2{aZ[2], aZ[3]},
               f32x2{aXN[2], aXN[3]}, f32x2{aHN[2], aHN[3]}, hB23);
    *(f16x4*)&H1w[widx] = pack4(hB01, hB23);
  };

  __syncthreads();

  // x B-frag source: lane (l15,q) reads x[b0+l15][t][q*8..q*8+7].
  // 2-deep prefetch in STATICALLY NAMED registers (slot0 = even t, slot1 = odd).
  const float* xbase = x + (size_t)(b0 + l15) * 4096 + q * 8;
  float4 xa0 = *(const float4*)xbase;
  float4 xb0 = *(const float4*)(xbase + 4);
  float4 xa1 = *(const float4*)(xbase + 32);
  float4 xb1 = *(const float4*)(xbase + 36);

  for (int t = 0; t < 128; t += 2) {
    // ---- phase 0: A step t, B step t-1.  Both consume H0[0] = h0(t-1).
    {
      const f16x8 g0 = *(const f16x8*)&H0[0][lane * 8];
      const f16x8 g1 = *(const f16x8*)&H0[0][512 + lane * 8];
      const float4 cxa = xa0, cxb = xb0;
      if (t + 2 < 128) {
        const float* xp = xbase + (t + 2) * 32;
        xa0 = *(const float4*)xp;
        xb0 = *(const float4*)(xp + 4);
      }
      if (t > 0) stepB(g0, g1, H1[0], H1[1]);
      stepA(g0, g1, H0[1], cxa, cxb);
    }
    LDS_BARRIER();

    // ---- phase 1: A step t+1, B step t.  Both consume H0[1] = h0(t).
    {
      const f16x8 g0 = *(const f16x8*)&H0[1][lane * 8];
      const f16x8 g1 = *(const f16x8*)&H0[1][512 + lane * 8];
      const float4 cxa = xa1, cxb = xb1;
      if (t + 3 < 128) {
        const float* xp = xbase + (t + 3) * 32;
        xa1 = *(const float4*)xp;
        xb1 = *(const float4*)(xp + 4);
      }
      stepB(g0, g1, H1[1], H1[0]);
      stepA(g0, g1, H0[0], cxa, cxb);
    }
    LDS_BARRIER();
  }
  // ---- epilogue: B step 127 (reads H0[0] = h0(127), H1[0] = h1(126))
  {
    const f16x8 g0 = *(const f16x8*)&H0[0][lane * 8];
    const f16x8 g1 = *(const f16x8*)&H0[0][512 + lane * 8];
    stepB(g0, g1, H1[0], H1[1]);
  }

  // ---- fc: out[b] = sum_i h1[i]*fcw[i] + fcb  (every wave holds 4 h1 rows)
  float partial = fw[0] * hB01[0] + fw[1] * hB01[1] + fw[2] * hB23[0] + fw[3] * hB23[1];
  partial += __shfl_down(partial, 16, 64);
  partial += __shfl_down(partial, 32, 64);
  if (lane < 16) red[wave][l15] = partial;
  __syncthreads();
  if (tid < 16) out[b0 + tid] = red[0][tid] + red[1][tid] + red[2][tid] + red[3][tid] + fcb0;
}

extern "C" void kernel_launch(void* const* d_in, const int* in_sizes, int n_in,
                              void* d_out, int out_size, void* d_ws, size_t ws_size,
                              hipStream_t stream) {
  (void)in_sizes; (void)n_in; (void)out_size; (void)d_ws; (void)ws_size;
  const float* x    = (const float*)d_in[0];
  const float* Wih0 = (const float*)d_in[1];
  const float* Whh0 = (const float*)d_in[2];
  const float* bih0 = (const float*)d_in[3];
  const float* bhh0 = (const float*)d_in[4];
  const float* Wih1 = (const float*)d_in[5];
  const float* Whh1 = (const float*)d_in[6];
  const float* bih1 = (const float*)d_in[7];
  const float* bhh1 = (const float*)d_in[8];
  const float* fcw  = (const float*)d_in[9];
  const float* fcb  = (const float*)d_in[10];
  float* out = (float*)d_out;

  gru_fused<<<256, 256, 0, stream>>>(x, Wih0, Whh0, bih0, bhh0,
                                     Wih1, Whh1, bih1, bhh1, fcw, fcb, out);
}